// Round 3
// baseline (346.559 us; speedup 1.0000x reference)
//
#include <hip/hip_runtime.h>

#define D_ 64
#define L_ 50
#define B_ 4096
#define T_ 100

__device__ __forceinline__ float sigmoidf_(float x) {
    return 1.0f / (1.0f + __expf(-x));
}

// One block (4 waves) per batch element b. Exactly 4 waves/EU (128 VGPR budget)
// so the fg_item_W column stays register-resident.
__global__ __launch_bounds__(256)
__attribute__((amdgpu_waves_per_eu(4, 4)))
void hgn_fused_kernel(
    const int* __restrict__ item_seq,          // [B,L]
    const int* __restrict__ user_ids,          // [B]
    const int* __restrict__ items_to_predict,  // [B,T]
    const float* __restrict__ user_emb_table,  // [U,D]
    const float* __restrict__ item_emb_table,  // [I,D]
    const float* __restrict__ fg_item_W,       // [D,D]
    const float* __restrict__ fg_item_b,       // [D]
    const float* __restrict__ fg_user_W,       // [D,D]
    const float* __restrict__ fg_user_b,       // [D]
    const float* __restrict__ ig_item,         // [D]
    const float* __restrict__ ig_user,         // [D,L]
    const float* __restrict__ W2,              // [I,D]
    const float* __restrict__ b2,              // [I]
    float* __restrict__ out)                   // [B,T]
{
    __shared__ __align__(16) float rows_sh[L_ * D_];   // staged item rows
    __shared__ float gi_sh[L_ * 65];                   // gated items, padded
    __shared__ float s_sh[L_];
    __shared__ __align__(16) float u_sh[D_];
    __shared__ __align__(16) float v_sh[D_];
    __shared__ float esum_sh[4 * D_];
    __shared__ int   idx_sh[L_];

    const int t    = threadIdx.x;
    const int lane = t & 63;
    const int wave = t >> 6;
    const int b    = blockIdx.x;

    if (t < L_) idx_sh[t] = item_seq[b * L_ + t];
    if (t >= 64 && t < 128) {
        const int uid = user_ids[b];
        u_sh[t - 64] = user_emb_table[(size_t)uid * D_ + (t - 64)];
    }
    __syncthreads();   // idx_sh / u_sh ready

    // ---- Coalesced staging of all 50 item rows into LDS.
    // i in [0,800): l = i>>4, quad k = i&15. 16 consecutive threads share a row.
    float4 r0, r1, r2, r3;
    {
        const int i0 = t, i1 = t + 256, i2 = t + 512, i3 = t + 768;
        r0 = ((const float4*)(item_emb_table + (size_t)idx_sh[i0 >> 4] * D_))[i0 & 15];
        r1 = ((const float4*)(item_emb_table + (size_t)idx_sh[i1 >> 4] * D_))[i1 & 15];
        r2 = ((const float4*)(item_emb_table + (size_t)idx_sh[i2 >> 4] * D_))[i2 & 15];
        if (i3 < L_ * 16)
            r3 = ((const float4*)(item_emb_table + (size_t)idx_sh[i3 >> 4] * D_))[i3 & 15];
    }

    // fg_item_W column `lane` into registers (overlaps with staging loads)
    float Wreg[64];
#pragma unroll
    for (int k = 0; k < 64; ++k) Wreg[k] = fg_item_W[k * 64 + lane];

    // gate bias: fg_item_b + fg_user_b + u @ fg_user_W (u from LDS broadcast)
    float gb0 = fg_item_b[lane], gb1 = fg_user_b[lane], gb2 = 0.f, gb3 = 0.f;
#pragma unroll
    for (int kk = 0; kk < 16; ++kk) {
        const float4 u4 = ((const float4*)u_sh)[kk];
        gb0 = fmaf(u4.x, fg_user_W[(4 * kk + 0) * 64 + lane], gb0);
        gb1 = fmaf(u4.y, fg_user_W[(4 * kk + 1) * 64 + lane], gb1);
        gb2 = fmaf(u4.z, fg_user_W[(4 * kk + 2) * 64 + lane], gb2);
        gb3 = fmaf(u4.w, fg_user_W[(4 * kk + 3) * 64 + lane], gb3);
    }
    const float gbias = (gb0 + gb1) + (gb2 + gb3);

    {
        float4* rows4 = (float4*)rows_sh;
        rows4[t] = r0;
        rows4[t + 256] = r1;
        rows4[t + 512] = r2;
        if (t + 768 < L_ * 16) rows4[t + 768] = r3;
    }
    __syncthreads();   // rows_sh ready

    // ---- Phase A: gating; wave handles l = wave, wave+4, ...
    float esum = 0.f;
    for (int l = wave; l < L_; l += 4) {
        const float* row = rows_sh + l * D_;
        const float e = row[lane];                      // per-lane, conflict-free
        float g0 = 0.f, g1 = 0.f, g2 = 0.f, g3 = 0.f;
#pragma unroll
        for (int kk = 0; kk < 16; ++kk) {
            const float4 e4 = ((const float4*)row)[kk]; // LDS broadcast (free)
            g0 = fmaf(e4.x, Wreg[4 * kk + 0], g0);
            g1 = fmaf(e4.y, Wreg[4 * kk + 1], g1);
            g2 = fmaf(e4.z, Wreg[4 * kk + 2], g2);
            g3 = fmaf(e4.w, Wreg[4 * kk + 3], g3);
        }
        const float gate = sigmoidf_(gbias + (g0 + g1) + (g2 + g3));
        gi_sh[l * 65 + lane] = e * gate;
        esum += e;
    }
    esum_sh[wave * 64 + lane] = esum;
    __syncthreads();   // gi_sh / esum_sh ready

    // ---- Phases B + C: wave 0 only
    if (wave == 0) {
        if (lane < L_) {           // B: instance score for item l = lane
            float p0 = 0.f, p1 = 0.f, p2 = 0.f, p3 = 0.f;
#pragma unroll
            for (int d = 0; d < 64; d += 4) {
                p0 = fmaf(gi_sh[lane * 65 + d + 0], ig_item[d + 0], p0);
                p1 = fmaf(gi_sh[lane * 65 + d + 1], ig_item[d + 1], p1);
                p2 = fmaf(gi_sh[lane * 65 + d + 2], ig_item[d + 2], p2);
                p3 = fmaf(gi_sh[lane * 65 + d + 3], ig_item[d + 3], p3);
                p0 = fmaf(u_sh[d + 0], ig_user[(d + 0) * L_ + lane], p0);
                p1 = fmaf(u_sh[d + 1], ig_user[(d + 1) * L_ + lane], p1);
                p2 = fmaf(u_sh[d + 2], ig_user[(d + 2) * L_ + lane], p2);
                p3 = fmaf(u_sh[d + 3], ig_user[(d + 3) * L_ + lane], p3);
            }
            s_sh[lane] = sigmoidf_((p0 + p1) + (p2 + p3));
        }
        // C: same-wave LDS dependency; compiler inserts lgkmcnt, no barrier.
        float a0 = 0.f, a1 = 0.f, ss = 0.f;
        for (int l = 0; l < L_; l += 2) {
            const float sA = s_sh[l], sB = s_sh[l + 1];
            a0 = fmaf(gi_sh[l * 65 + lane], sA, a0);
            a1 = fmaf(gi_sh[(l + 1) * 65 + lane], sB, a1);
            ss += sA + sB;
        }
        const float es = esum_sh[lane] + esum_sh[64 + lane] +
                         esum_sh[128 + lane] + esum_sh[192 + lane];
        v_sh[lane] = u_sh[lane] + (a0 + a1) / ss + es;
    }
    __syncthreads();   // v_sh ready

    // ---- Phase D: scoring, one thread per t
    if (t < T_) {
        const int idx = items_to_predict[b * T_ + t];
        const float* wrow = W2 + (size_t)idx * D_;
        float r0s = 0.f, r1s = 0.f, r2s = 0.f, r3s = 0.f;
#pragma unroll
        for (int kk = 0; kk < 16; ++kk) {
            const float4 w4 = ((const float4*)wrow)[kk];   // per-lane gather
            const float4 v4 = ((const float4*)v_sh)[kk];   // LDS broadcast
            r0s = fmaf(v4.x, w4.x, r0s);
            r1s = fmaf(v4.y, w4.y, r1s);
            r2s = fmaf(v4.z, w4.z, r2s);
            r3s = fmaf(v4.w, w4.w, r3s);
        }
        out[b * T_ + t] = ((r0s + r1s) + (r2s + r3s)) + b2[idx];
    }
}

extern "C" void kernel_launch(void* const* d_in, const int* in_sizes, int n_in,
                              void* d_out, int out_size, void* d_ws, size_t ws_size,
                              hipStream_t stream) {
    const int*   item_seq   = (const int*)d_in[0];
    const int*   user_ids   = (const int*)d_in[1];
    const int*   items_pred = (const int*)d_in[2];
    const float* uet        = (const float*)d_in[3];
    const float* iet        = (const float*)d_in[4];
    const float* fgiW       = (const float*)d_in[5];
    const float* fgib       = (const float*)d_in[6];
    const float* fguW       = (const float*)d_in[7];
    const float* fgub       = (const float*)d_in[8];
    const float* igi        = (const float*)d_in[9];
    const float* igu        = (const float*)d_in[10];
    const float* W2         = (const float*)d_in[11];
    const float* b2t        = (const float*)d_in[12];

    hgn_fused_kernel<<<B_, 256, 0, stream>>>(
        item_seq, user_ids, items_pred, uet, iet,
        fgiW, fgib, fguW, fgub, igi, igu, W2, b2t, (float*)d_out);
}

// Round 4
// 239.427 us; speedup vs baseline: 1.4474x; 1.4474x over previous
//
#include <hip/hip_runtime.h>

#define D_ 64
#define L_ 50
#define B_ 4096
#define T_ 100
#define SP 65   // padded stride for partial/gi buffers (banks (l+d)%32 -> 2-way, free)

__device__ __forceinline__ float sigmoidf_(float x) {
    return 1.0f / (1.0f + __expf(-x));
}

// One block (4 waves) per batch b. Designed to fit the observed 64-VGPR cap:
// wave w: h=w&1 owns K-half [32h,32h+32) -> Wreg[32]; g=w>>1 owns items [25g,25g+25).
// Gate logits computed as two K-half partials summed through LDS.
__global__ __launch_bounds__(256)
void hgn_fused_kernel(
    const int* __restrict__ item_seq,          // [B,L]
    const int* __restrict__ user_ids,          // [B]
    const int* __restrict__ items_to_predict,  // [B,T]
    const float* __restrict__ user_emb_table,  // [U,D]
    const float* __restrict__ item_emb_table,  // [I,D]
    const float* __restrict__ fg_item_W,       // [D,D]
    const float* __restrict__ fg_item_b,       // [D]
    const float* __restrict__ fg_user_W,       // [D,D]
    const float* __restrict__ fg_user_b,       // [D]
    const float* __restrict__ ig_item,         // [D]
    const float* __restrict__ ig_user,         // [D,L]
    const float* __restrict__ W2,              // [I,D]
    const float* __restrict__ b2,              // [I]
    float* __restrict__ out)                   // [B,T]
{
    __shared__ float part0_sh[L_ * SP];                // K-half-0 partials, then gi
    __shared__ float part1_sh[L_ * SP];                // K-half-1 partials
    __shared__ __align__(16) float e_sh[L_ * D_];      // raw item embeddings
    __shared__ __align__(16) float u_sh[D_];
    __shared__ __align__(16) float v_sh[D_];
    __shared__ float s_sh[L_];
    __shared__ float esum_sh[2 * D_];
    __shared__ int   idx_sh[L_];

    const int t    = threadIdx.x;
    const int lane = t & 63;
    const int wave = t >> 6;
    const int b    = blockIdx.x;
    const int h    = wave & 1;    // K-half
    const int g    = wave >> 1;   // item group

    if (t < L_) idx_sh[t] = item_seq[b * L_ + t];
    if (t >= 64 && t < 128) {
        const int uid = user_ids[b];
        u_sh[t - 64] = user_emb_table[(size_t)uid * D_ + (t - 64)];
    }
    __syncthreads();   // idx_sh / u_sh ready

    const int k0 = 32 * h;

    // Half-column of fg_item_W in registers: Wreg[j] = W[k0+j][lane]  (32 VGPRs)
    float Wreg[32];
#pragma unroll
    for (int j = 0; j < 32; ++j)
        Wreg[j] = fg_item_W[(k0 + j) * D_ + lane];

    // Gate-bias half (biases folded into h==0):
    float gb = (h == 0) ? (fg_item_b[lane] + fg_user_b[lane]) : 0.f;
#pragma unroll
    for (int j = 0; j < 32; ++j)
        gb = fmaf(u_sh[k0 + j], fg_user_W[(k0 + j) * D_ + lane], gb);

    // ---- Phase A: K-half partial gate logits for this wave's 25 items.
    float esum = 0.f;
    const int lbase = 25 * g;
    for (int l = 0; l < 25; ++l) {
        const int lg = lbase + l;
        // wave-uniform index -> scalar base -> row loads go to SGPRs (s_load)
        const int sidx = __builtin_amdgcn_readfirstlane(idx_sh[lg]);
        const float* rowk = item_emb_table + (size_t)sidx * D_ + k0;
        float g0 = 0.f, g1 = 0.f, g2 = 0.f, g3 = 0.f;
#pragma unroll
        for (int jj = 0; jj < 8; ++jj) {
            const float4 e4 = ((const float4*)rowk)[jj];   // scalar/uniform load
            g0 = fmaf(e4.x, Wreg[4 * jj + 0], g0);
            g1 = fmaf(e4.y, Wreg[4 * jj + 1], g1);
            g2 = fmaf(e4.z, Wreg[4 * jj + 2], g2);
            g3 = fmaf(e4.w, Wreg[4 * jj + 3], g3);
        }
        const float p = gb + (g0 + g1) + (g2 + g3);
        if (h == 0) {
            const float e = item_emb_table[(size_t)sidx * D_ + lane];  // coalesced
            e_sh[lg * D_ + lane] = e;
            esum += e;
            part0_sh[lg * SP + lane] = p;
        } else {
            part1_sh[lg * SP + lane] = p;
        }
    }
    if (h == 0) esum_sh[g * D_ + lane] = esum;
    __syncthreads();   // partials / e_sh / esum_sh ready

    // ---- Finalize: gate = sigmoid(p0+p1); gi = e*gate (in-place over part0)
    for (int i = t; i < L_ * D_; i += 256) {
        const int l = i >> 6, d = i & 63;
        const int a = l * SP + d;
        const float gate = sigmoidf_(part0_sh[a] + part1_sh[a]);
        part0_sh[a] = e_sh[i] * gate;
    }
    __syncthreads();   // gi ready

    // ---- Phases B + C: wave 0 only
    if (wave == 0) {
        if (lane < L_) {          // B: instance score for item l = lane
            float p0 = 0.f, p1 = 0.f, p2 = 0.f, p3 = 0.f;
#pragma unroll
            for (int d = 0; d < D_; d += 4) {
                p0 = fmaf(part0_sh[lane * SP + d + 0], ig_item[d + 0], p0);
                p1 = fmaf(part0_sh[lane * SP + d + 1], ig_item[d + 1], p1);
                p2 = fmaf(part0_sh[lane * SP + d + 2], ig_item[d + 2], p2);
                p3 = fmaf(part0_sh[lane * SP + d + 3], ig_item[d + 3], p3);
                p0 = fmaf(u_sh[d + 0], ig_user[(d + 0) * L_ + lane], p0);
                p1 = fmaf(u_sh[d + 1], ig_user[(d + 1) * L_ + lane], p1);
                p2 = fmaf(u_sh[d + 2], ig_user[(d + 2) * L_ + lane], p2);
                p3 = fmaf(u_sh[d + 3], ig_user[(d + 3) * L_ + lane], p3);
            }
            s_sh[lane] = sigmoidf_((p0 + p1) + (p2 + p3));
        }
        // C: same-wave LDS dependency; compiler inserts lgkmcnt, no barrier.
        float a0 = 0.f, a1 = 0.f, ss = 0.f;
        for (int l = 0; l < L_; l += 2) {
            const float sA = s_sh[l], sB = s_sh[l + 1];
            a0 = fmaf(part0_sh[l * SP + lane], sA, a0);
            a1 = fmaf(part0_sh[(l + 1) * SP + lane], sB, a1);
            ss += sA + sB;
        }
        v_sh[lane] = u_sh[lane] + (a0 + a1) / ss +
                     esum_sh[lane] + esum_sh[D_ + lane];
    }
    __syncthreads();   // v_sh ready

    // ---- Phase D: scoring, one thread per t
    if (t < T_) {
        const int idx = items_to_predict[b * T_ + t];
        const float* wrow = W2 + (size_t)idx * D_;
        float r0 = 0.f, r1 = 0.f, r2 = 0.f, r3 = 0.f;
#pragma unroll
        for (int kk = 0; kk < 16; ++kk) {
            const float4 w4 = ((const float4*)wrow)[kk];   // per-lane gather
            const float4 v4 = ((const float4*)v_sh)[kk];   // LDS broadcast
            r0 = fmaf(v4.x, w4.x, r0);
            r1 = fmaf(v4.y, w4.y, r1);
            r2 = fmaf(v4.z, w4.z, r2);
            r3 = fmaf(v4.w, w4.w, r3);
        }
        out[b * T_ + t] = ((r0 + r1) + (r2 + r3)) + b2[idx];
    }
}

extern "C" void kernel_launch(void* const* d_in, const int* in_sizes, int n_in,
                              void* d_out, int out_size, void* d_ws, size_t ws_size,
                              hipStream_t stream) {
    const int*   item_seq   = (const int*)d_in[0];
    const int*   user_ids   = (const int*)d_in[1];
    const int*   items_pred = (const int*)d_in[2];
    const float* uet        = (const float*)d_in[3];
    const float* iet        = (const float*)d_in[4];
    const float* fgiW       = (const float*)d_in[5];
    const float* fgib       = (const float*)d_in[6];
    const float* fguW       = (const float*)d_in[7];
    const float* fgub       = (const float*)d_in[8];
    const float* igi        = (const float*)d_in[9];
    const float* igu        = (const float*)d_in[10];
    const float* W2         = (const float*)d_in[11];
    const float* b2t        = (const float*)d_in[12];

    hgn_fused_kernel<<<B_, 256, 0, stream>>>(
        item_seq, user_ids, items_pred, uet, iet,
        fgiW, fgib, fguW, fgub, igi, igu, W2, b2t, (float*)d_out);
}

// Round 5
// 180.585 us; speedup vs baseline: 1.9191x; 1.3258x over previous
//
#include <hip/hip_runtime.h>

#define D_ 64
#define L_ 50
#define B_ 4096
#define T_ 100
#define SP 65   // padded stride for partial/gi buffers ((l+lane)%32 -> 2-way, free)

__device__ __forceinline__ float sigmoidf_(float x) {
    return 1.0f / (1.0f + __expf(-x));
}

// One block (4 waves) per batch b. Fits the observed 64-VGPR cap:
// wave w: h=w&1 owns K-half [32h,32h+32) -> Wreg[32]; g=w>>1 owns items [25g,25g+25).
// Item rows staged ONCE coalesced into LDS; inner loop reads them via
// LDS broadcast (same-address ds_read_b128 ~ free). No scalar-path gathers.
__global__ __launch_bounds__(256)
void hgn_fused_kernel(
    const int* __restrict__ item_seq,          // [B,L]
    const int* __restrict__ user_ids,          // [B]
    const int* __restrict__ items_to_predict,  // [B,T]
    const float* __restrict__ user_emb_table,  // [U,D]
    const float* __restrict__ item_emb_table,  // [I,D]
    const float* __restrict__ fg_item_W,       // [D,D]
    const float* __restrict__ fg_item_b,       // [D]
    const float* __restrict__ fg_user_W,       // [D,D]
    const float* __restrict__ fg_user_b,       // [D]
    const float* __restrict__ ig_item,         // [D]
    const float* __restrict__ ig_user,         // [D,L]
    const float* __restrict__ W2,              // [I,D]
    const float* __restrict__ b2,              // [I]
    float* __restrict__ out)                   // [B,T]
{
    __shared__ __align__(16) float e_sh[L_ * D_];      // staged item rows (f32)
    __shared__ float part0_sh[L_ * SP];                // K-half-0 partials -> gi
    __shared__ float part1_sh[L_ * SP];                // K-half-1 partials
    __shared__ __align__(16) float u_sh[D_];
    __shared__ __align__(16) float v_sh[D_];
    __shared__ float s_sh[L_];
    __shared__ float esum_sh[2 * D_];
    __shared__ int   idx_sh[L_];

    const int t    = threadIdx.x;
    const int lane = t & 63;
    const int wave = t >> 6;
    const int b    = blockIdx.x;
    const int h    = wave & 1;    // K-half
    const int g    = wave >> 1;   // item group

    if (t < L_) idx_sh[t] = item_seq[b * L_ + t];
    if (t >= 64 && t < 128) {
        const int uid = user_ids[b];
        u_sh[t - 64] = user_emb_table[(size_t)uid * D_ + (t - 64)];
    }
    __syncthreads();   // idx_sh / u_sh ready

    // ---- Coalesced staging of all 50 item rows into LDS (800 float4 loads).
    // i in [0,800): item l = i>>4, quad = i&15; 16 consecutive threads share a row.
    {
        const int i0 = t, i1 = t + 256, i2 = t + 512, i3 = t + 768;
        float4 r0 = ((const float4*)(item_emb_table + (size_t)idx_sh[i0 >> 4] * D_))[i0 & 15];
        float4 r1 = ((const float4*)(item_emb_table + (size_t)idx_sh[i1 >> 4] * D_))[i1 & 15];
        float4 r2 = ((const float4*)(item_emb_table + (size_t)idx_sh[i2 >> 4] * D_))[i2 & 15];
        float4 r3;
        if (i3 < L_ * 16)
            r3 = ((const float4*)(item_emb_table + (size_t)idx_sh[i3 >> 4] * D_))[i3 & 15];
        float4* e4 = (float4*)e_sh;
        e4[i0] = r0;
        e4[i1] = r1;
        e4[i2] = r2;
        if (i3 < L_ * 16) e4[i3] = r3;
    }

    const int k0 = 32 * h;

    // Half-column of fg_item_W in registers: Wreg[j] = W[k0+j][lane]  (32 VGPRs,
    // coalesced global loads, L1-hot; loaded while staging is in flight)
    float Wreg[32];
#pragma unroll
    for (int j = 0; j < 32; ++j)
        Wreg[j] = fg_item_W[(k0 + j) * D_ + lane];

    // Gate-bias half (biases folded into h==0):
    float gb = (h == 0) ? (fg_item_b[lane] + fg_user_b[lane]) : 0.f;
#pragma unroll
    for (int j = 0; j < 32; ++j)
        gb = fmaf(u_sh[k0 + j], fg_user_W[(k0 + j) * D_ + lane], gb);

    __syncthreads();   // e_sh ready

    // ---- Phase A: K-half partial gate logits for this wave's 25 items.
    // Inner loop: 8 LDS-broadcast float4 reads + 32 FMAs. No global traffic.
    float esum = 0.f;
    const int lbase = 25 * g;
    for (int l = 0; l < 25; ++l) {
        const int lg = lbase + l;
        const float* rowk = e_sh + lg * D_ + k0;
        float g0 = 0.f, g1 = 0.f, g2 = 0.f, g3 = 0.f;
#pragma unroll
        for (int jj = 0; jj < 8; ++jj) {
            const float4 e4 = ((const float4*)rowk)[jj];   // LDS broadcast (free)
            g0 = fmaf(e4.x, Wreg[4 * jj + 0], g0);
            g1 = fmaf(e4.y, Wreg[4 * jj + 1], g1);
            g2 = fmaf(e4.z, Wreg[4 * jj + 2], g2);
            g3 = fmaf(e4.w, Wreg[4 * jj + 3], g3);
        }
        const float p = gb + (g0 + g1) + (g2 + g3);
        if (h == 0) {
            const float e = e_sh[lg * D_ + lane];          // per-lane, conflict-free
            esum += e;
            part0_sh[lg * SP + lane] = p;
        } else {
            part1_sh[lg * SP + lane] = p;
        }
    }
    if (h == 0) esum_sh[g * D_ + lane] = esum;
    __syncthreads();   // partials / esum_sh ready

    // ---- Finalize: gate = sigmoid(p0+p1); gi = e*gate (in-place over part0)
    for (int i = t; i < L_ * D_; i += 256) {
        const int l = i >> 6, d = i & 63;
        const int a = l * SP + d;
        const float gate = sigmoidf_(part0_sh[a] + part1_sh[a]);
        part0_sh[a] = e_sh[i] * gate;
    }
    __syncthreads();   // gi ready

    // ---- Phases B + C: wave 0 only
    if (wave == 0) {
        if (lane < L_) {          // B: instance score for item l = lane
            float p0 = 0.f, p1 = 0.f, p2 = 0.f, p3 = 0.f;
#pragma unroll
            for (int d = 0; d < D_; d += 4) {
                p0 = fmaf(part0_sh[lane * SP + d + 0], ig_item[d + 0], p0);
                p1 = fmaf(part0_sh[lane * SP + d + 1], ig_item[d + 1], p1);
                p2 = fmaf(part0_sh[lane * SP + d + 2], ig_item[d + 2], p2);
                p3 = fmaf(part0_sh[lane * SP + d + 3], ig_item[d + 3], p3);
                p0 = fmaf(u_sh[d + 0], ig_user[(d + 0) * L_ + lane], p0);
                p1 = fmaf(u_sh[d + 1], ig_user[(d + 1) * L_ + lane], p1);
                p2 = fmaf(u_sh[d + 2], ig_user[(d + 2) * L_ + lane], p2);
                p3 = fmaf(u_sh[d + 3], ig_user[(d + 3) * L_ + lane], p3);
            }
            s_sh[lane] = sigmoidf_((p0 + p1) + (p2 + p3));
        }
        // C: same-wave LDS dependency; compiler inserts lgkmcnt, no barrier.
        float a0 = 0.f, a1 = 0.f, ss = 0.f;
        for (int l = 0; l < L_; l += 2) {
            const float sA = s_sh[l], sB = s_sh[l + 1];
            a0 = fmaf(part0_sh[l * SP + lane], sA, a0);
            a1 = fmaf(part0_sh[(l + 1) * SP + lane], sB, a1);
            ss += sA + sB;
        }
        v_sh[lane] = u_sh[lane] + (a0 + a1) / ss +
                     esum_sh[lane] + esum_sh[D_ + lane];
    }
    __syncthreads();   // v_sh ready

    // ---- Phase D: scoring, one thread per t
    if (t < T_) {
        const int idx = items_to_predict[b * T_ + t];
        const float* wrow = W2 + (size_t)idx * D_;
        float r0 = 0.f, r1 = 0.f, r2 = 0.f, r3 = 0.f;
#pragma unroll
        for (int kk = 0; kk < 16; ++kk) {
            const float4 w4 = ((const float4*)wrow)[kk];   // per-lane gather
            const float4 v4 = ((const float4*)v_sh)[kk];   // LDS broadcast
            r0 = fmaf(v4.x, w4.x, r0);
            r1 = fmaf(v4.y, w4.y, r1);
            r2 = fmaf(v4.z, w4.z, r2);
            r3 = fmaf(v4.w, w4.w, r3);
        }
        out[b * T_ + t] = ((r0 + r1) + (r2 + r3)) + b2[idx];
    }
}

extern "C" void kernel_launch(void* const* d_in, const int* in_sizes, int n_in,
                              void* d_out, int out_size, void* d_ws, size_t ws_size,
                              hipStream_t stream) {
    const int*   item_seq   = (const int*)d_in[0];
    const int*   user_ids   = (const int*)d_in[1];
    const int*   items_pred = (const int*)d_in[2];
    const float* uet        = (const float*)d_in[3];
    const float* iet        = (const float*)d_in[4];
    const float* fgiW       = (const float*)d_in[5];
    const float* fgib       = (const float*)d_in[6];
    const float* fguW       = (const float*)d_in[7];
    const float* fgub       = (const float*)d_in[8];
    const float* igi        = (const float*)d_in[9];
    const float* igu        = (const float*)d_in[10];
    const float* W2         = (const float*)d_in[11];
    const float* b2t        = (const float*)d_in[12];

    hgn_fused_kernel<<<B_, 256, 0, stream>>>(
        item_seq, user_ids, items_pred, uet, iet,
        fgiW, fgib, fguW, fgub, igi, igu, W2, b2t, (float*)d_out);
}

// Round 6
// 169.199 us; speedup vs baseline: 2.0482x; 1.0673x over previous
//
#include <hip/hip_runtime.h>

#define D_ 64
#define L_ 50
#define B_ 4096
#define T_ 100
#define SP 65    // f32 logit/gi buffer stride (padding vs power-of-2)
#define RS 72    // bf16 row stride for eb/wbT (144 B -> 4m%32 bank rotation)

typedef __attribute__((ext_vector_type(8))) short  short8;   // 8 bf16 = 4 VGPRs
typedef __attribute__((ext_vector_type(4))) float  float4v;  // MFMA acc
typedef __attribute__((ext_vector_type(4))) unsigned short ushort4v;

__device__ __forceinline__ float sigmoidf_(float x) {
    return 1.0f / (1.0f + __expf(-x));
}
__device__ __forceinline__ unsigned short f2bf(float x) {   // RNE f32->bf16
    unsigned u = __builtin_bit_cast(unsigned, x);
    return (unsigned short)((u + 0x7fffu + ((u >> 16) & 1u)) >> 16);
}
__device__ __forceinline__ float bf2f(unsigned short s) {
    return __builtin_bit_cast(float, (unsigned)s << 16);
}

// One block (4 waves) per batch b.
// Gate matmul P[50x64] = E @ W on the MFMA pipe (bf16, 8 mfma/wave).
// Wave w owns M-tile rows [16w,16w+16). E,W^T staged once as bf16 in LDS.
__global__ __launch_bounds__(256)
void hgn_fused_kernel(
    const int* __restrict__ item_seq,          // [B,L]
    const int* __restrict__ user_ids,          // [B]
    const int* __restrict__ items_to_predict,  // [B,T]
    const float* __restrict__ user_emb_table,  // [U,D]
    const float* __restrict__ item_emb_table,  // [I,D]
    const float* __restrict__ fg_item_W,       // [D,D]
    const float* __restrict__ fg_item_b,       // [D]
    const float* __restrict__ fg_user_W,       // [D,D]
    const float* __restrict__ fg_user_b,       // [D]
    const float* __restrict__ ig_item,         // [D]
    const float* __restrict__ ig_user,         // [D,L]
    const float* __restrict__ W2,              // [I,D]
    const float* __restrict__ b2,              // [I]
    float* __restrict__ out)                   // [B,T]
{
    __shared__ unsigned short eb_sh[64 * RS];          // E rows, bf16 (rows>=50 zero)
    __shared__ unsigned short wbT_sh[64 * RS];         // W^T rows, bf16
    __shared__ float part_sh[L_ * SP];                 // gate logits -> gi
    __shared__ __align__(16) float u_sh[D_];
    __shared__ __align__(16) float v_sh[D_];
    __shared__ float gb_sh[D_];
    __shared__ float s_sh[L_];
    __shared__ float esum_sh[D_];
    __shared__ int   idx_sh[L_];

    const int t    = threadIdx.x;
    const int lane = t & 63;
    const int wave = t >> 6;
    const int b    = blockIdx.x;

    if (t < L_) idx_sh[t] = item_seq[b * L_ + t];
    if (t >= 64 && t < 128) {
        const int uid = user_ids[b];
        u_sh[t - 64] = user_emb_table[(size_t)uid * D_ + (t - 64)];
    }
    // zero-pad E rows 50..63 (incl. stride pad)
    for (int i = t; i < 14 * RS; i += 256) eb_sh[50 * RS + i] = 0;
    __syncthreads();   // idx_sh / u_sh ready

    if (wave == 1) {
        // gbias[d] = fg_item_b + fg_user_b + u @ fg_user_W   (f32, coalesced)
        float gbv = fg_item_b[lane] + fg_user_b[lane];
#pragma unroll
        for (int k = 0; k < D_; ++k)
            gbv = fmaf(u_sh[k], fg_user_W[k * D_ + lane], gbv);
        gb_sh[lane] = gbv;
    } else {
        // waves 0,2,3 (192 threads): stage E and W^T as bf16
        const int s = (wave == 0) ? t : (t - 64);
        for (int i = s; i < L_ * 16; i += 192) {       // E: 800 float4
            const int l = i >> 4, qd = i & 15;
            const float4 r = ((const float4*)(item_emb_table + (size_t)idx_sh[l] * D_))[qd];
            ushort4v o = { f2bf(r.x), f2bf(r.y), f2bf(r.z), f2bf(r.w) };
            *(ushort4v*)&eb_sh[l * RS + qd * 4] = o;   // 8B aligned
        }
        for (int i = s; i < 1024; i += 192) {          // W: 1024 float4, transposed
            const int k = i >> 4, c4 = (i & 15) * 4;
            const float4 r = ((const float4*)(fg_item_W + k * D_))[i & 15];
            wbT_sh[(c4 + 0) * RS + k] = f2bf(r.x);
            wbT_sh[(c4 + 1) * RS + k] = f2bf(r.y);
            wbT_sh[(c4 + 2) * RS + k] = f2bf(r.z);
            wbT_sh[(c4 + 3) * RS + k] = f2bf(r.w);
        }
    }
    __syncthreads();   // eb/wbT/gb ready

    // ---- MFMA gate matmul: wave w -> rows [16w,16w+16)
    {
        const int m = lane & 15, q = lane >> 4;
        const int arow = 16 * wave + m;
        const short8 a0 = *(const short8*)&eb_sh[arow * RS + q * 8];       // k 0..31
        const short8 a1 = *(const short8*)&eb_sh[arow * RS + 32 + q * 8];  // k 32..63
#pragma unroll
        for (int n = 0; n < 4; ++n) {
            const int bcol = 16 * n + m;
            const short8 b0 = *(const short8*)&wbT_sh[bcol * RS + q * 8];
            const short8 b1 = *(const short8*)&wbT_sh[bcol * RS + 32 + q * 8];
            float4v acc = {0.f, 0.f, 0.f, 0.f};
            acc = __builtin_amdgcn_mfma_f32_16x16x32_bf16(a0, b0, acc, 0, 0, 0);
            acc = __builtin_amdgcn_mfma_f32_16x16x32_bf16(a1, b1, acc, 0, 0, 0);
#pragma unroll
            for (int r = 0; r < 4; ++r) {
                const int l = 16 * wave + q * 4 + r;   // C/D: row=q*4+r, col=16n+m
                if (l < L_) part_sh[l * SP + 16 * n + m] = acc[r];
            }
        }
    }
    __syncthreads();   // logits ready

    // ---- Finalize: gate = sigmoid(logit + gbias); gi = e * gate
    for (int i = t; i < L_ * D_; i += 256) {
        const int l = i >> 6, d = i & 63;
        const float e = bf2f(eb_sh[l * RS + d]);
        const float gate = sigmoidf_(part_sh[l * SP + d] + gb_sh[d]);
        part_sh[l * SP + d] = e * gate;
    }
    __syncthreads();   // gi ready

    // ---- Phase B (wave 0) + esum (wave 1), concurrent
    if (wave == 0 && lane < L_) {      // instance score for item l = lane
        float p0 = 0.f, p1 = 0.f, p2 = 0.f, p3 = 0.f;
#pragma unroll
        for (int d = 0; d < D_; d += 4) {
            p0 = fmaf(part_sh[lane * SP + d + 0], ig_item[d + 0], p0);
            p1 = fmaf(part_sh[lane * SP + d + 1], ig_item[d + 1], p1);
            p2 = fmaf(part_sh[lane * SP + d + 2], ig_item[d + 2], p2);
            p3 = fmaf(part_sh[lane * SP + d + 3], ig_item[d + 3], p3);
            p0 = fmaf(u_sh[d + 0], ig_user[(d + 0) * L_ + lane], p0);
            p1 = fmaf(u_sh[d + 1], ig_user[(d + 1) * L_ + lane], p1);
            p2 = fmaf(u_sh[d + 2], ig_user[(d + 2) * L_ + lane], p2);
            p3 = fmaf(u_sh[d + 3], ig_user[(d + 3) * L_ + lane], p3);
        }
        s_sh[lane] = sigmoidf_((p0 + p1) + (p2 + p3));
    }
    if (wave == 1) {                   // esum[d] = sum_l e[l][d]
        float es = 0.f;
#pragma unroll 2
        for (int l = 0; l < L_; ++l) es += bf2f(eb_sh[l * RS + lane]);
        esum_sh[lane] = es;
    }
    __syncthreads();   // s_sh / esum_sh ready

    // ---- Phase C: wave 0: v = u + union/ssum + esum
    if (wave == 0) {
        float a0 = 0.f, a1 = 0.f, ss = 0.f;
        for (int l = 0; l < L_; l += 2) {
            const float sA = s_sh[l], sB = s_sh[l + 1];
            a0 = fmaf(part_sh[l * SP + lane], sA, a0);
            a1 = fmaf(part_sh[(l + 1) * SP + lane], sB, a1);
            ss += sA + sB;
        }
        v_sh[lane] = u_sh[lane] + (a0 + a1) / ss + esum_sh[lane];
    }
    __syncthreads();   // v_sh ready

    // ---- Phase D: 2 threads per (b,t): each half-row dot, combine via shfl
    if (t < 2 * T_) {
        const int tt = t >> 1, half = t & 1;
        const int idx = items_to_predict[b * T_ + tt];
        const float* wrow  = W2 + (size_t)idx * D_ + half * 32;
        const float* vhalf = v_sh + half * 32;
        float r0 = 0.f, r1 = 0.f, r2 = 0.f, r3 = 0.f;
#pragma unroll
        for (int kk = 0; kk < 8; ++kk) {
            const float4 w4 = ((const float4*)wrow)[kk];    // per-lane gather
            const float4 v4 = ((const float4*)vhalf)[kk];   // LDS broadcast-ish
            r0 = fmaf(v4.x, w4.x, r0);
            r1 = fmaf(v4.y, w4.y, r1);
            r2 = fmaf(v4.z, w4.z, r2);
            r3 = fmaf(v4.w, w4.w, r3);
        }
        float r = (r0 + r1) + (r2 + r3);
        r += __shfl_xor(r, 1, 64);                          // pair same wave
        if (half == 0) out[b * T_ + tt] = r + b2[idx];
    }
}

extern "C" void kernel_launch(void* const* d_in, const int* in_sizes, int n_in,
                              void* d_out, int out_size, void* d_ws, size_t ws_size,
                              hipStream_t stream) {
    const int*   item_seq   = (const int*)d_in[0];
    const int*   user_ids   = (const int*)d_in[1];
    const int*   items_pred = (const int*)d_in[2];
    const float* uet        = (const float*)d_in[3];
    const float* iet        = (const float*)d_in[4];
    const float* fgiW       = (const float*)d_in[5];
    const float* fgib       = (const float*)d_in[6];
    const float* fguW       = (const float*)d_in[7];
    const float* fgub       = (const float*)d_in[8];
    const float* igi        = (const float*)d_in[9];
    const float* igu        = (const float*)d_in[10];
    const float* W2         = (const float*)d_in[11];
    const float* b2t        = (const float*)d_in[12];

    hgn_fused_kernel<<<B_, 256, 0, stream>>>(
        item_seq, user_ids, items_pred, uet, iet,
        fgiW, fgib, fguW, fgub, igi, igu, W2, b2t, (float*)d_out);
}

// Round 7
// 165.350 us; speedup vs baseline: 2.0959x; 1.0233x over previous
//
#include <hip/hip_runtime.h>

#define D_ 64
#define L_ 50
#define B_ 4096
#define T_ 100
#define SP 65    // f32 gi buffer stride
#define RS 72    // bf16 eb row stride (144 B, 16B-aligned for b128)

typedef __attribute__((ext_vector_type(8))) short  short8;   // 8 bf16 = 4 VGPRs
typedef __attribute__((ext_vector_type(4))) float  float4v;  // MFMA acc
typedef __attribute__((ext_vector_type(4))) unsigned short ushort4v;

__device__ __forceinline__ float sigmoidf_(float x) {
    return 1.0f / (1.0f + __expf(-x));
}
__device__ __forceinline__ unsigned short f2bf(float x) {   // RNE f32->bf16
    unsigned u = __builtin_bit_cast(unsigned, x);
    return (unsigned short)((u + 0x7fffu + ((u >> 16) & 1u)) >> 16);
}
__device__ __forceinline__ float bf2f(unsigned short s) {
    return __builtin_bit_cast(float, (unsigned)s << 16);
}

// Prelude (runs once per launch, ~16 KB): wbT[c*64+k] = bf16(W[k][c])
__global__ __launch_bounds__(256) void hgn_transpose_w(
    const float* __restrict__ fg_item_W, unsigned short* __restrict__ wbT)
{
    const int i = blockIdx.x * 256 + threadIdx.x;   // i over 4096
    const int k = i >> 6, c = i & 63;
    wbT[c * 64 + k] = f2bf(fg_item_W[i]);           // coalesced read, scattered write
}

// Main: one block (4 waves) per batch b.
__global__ __launch_bounds__(256) void hgn_fused_kernel(
    const int* __restrict__ item_seq,          // [B,L]
    const int* __restrict__ user_ids,          // [B]
    const int* __restrict__ items_to_predict,  // [B,T]
    const float* __restrict__ user_emb_table,  // [U,D]
    const float* __restrict__ item_emb_table,  // [I,D]
    const unsigned short* __restrict__ wbT,    // [64,64] bf16 W^T (precomputed)
    const float* __restrict__ fg_item_b,       // [D]
    const float* __restrict__ fg_user_W,       // [D,D]
    const float* __restrict__ fg_user_b,       // [D]
    const float* __restrict__ ig_item,         // [D]
    const float* __restrict__ ig_user,         // [D,L]
    const float* __restrict__ W2,              // [I,D]
    const float* __restrict__ b2,              // [I]
    float* __restrict__ out)                   // [B,T]
{
    __shared__ unsigned short eb_sh[64 * RS];          // E rows bf16 (rows>=50 garbage, harmless)
    __shared__ float part_sh[L_ * SP];                 // gi
    __shared__ __align__(16) float u_sh[D_];
    __shared__ __align__(16) float v_sh[D_];
    __shared__ float gb_sh[D_];
    __shared__ float s_sh[L_];
    __shared__ float bp_sh[2][64];                     // B-phase d-half partials
    __shared__ float esum_sh[D_];
    __shared__ int   idx_sh[L_];

    const int t    = threadIdx.x;
    const int lane = t & 63;
    const int wave = t >> 6;
    const int b    = blockIdx.x;

    if (t < L_) idx_sh[t] = item_seq[b * L_ + t];
    if (t >= 64 && t < 128) {
        const int uid = user_ids[b];
        u_sh[t - 64] = user_emb_table[(size_t)uid * D_ + (t - 64)];
    }
    __syncthreads();   // idx_sh / u_sh ready

    if (wave == 3) {
        // gbias[d] = fg_item_b + fg_user_b + u @ fg_user_W (coalesced, L1-hot)
        float g0 = fg_item_b[lane], g1 = fg_user_b[lane], g2 = 0.f, g3 = 0.f;
#pragma unroll
        for (int k = 0; k < D_; k += 4) {
            g0 = fmaf(u_sh[k + 0], fg_user_W[(k + 0) * D_ + lane], g0);
            g1 = fmaf(u_sh[k + 1], fg_user_W[(k + 1) * D_ + lane], g1);
            g2 = fmaf(u_sh[k + 2], fg_user_W[(k + 2) * D_ + lane], g2);
            g3 = fmaf(u_sh[k + 3], fg_user_W[(k + 3) * D_ + lane], g3);
        }
        gb_sh[lane] = (g0 + g1) + (g2 + g3);
    } else {
        // waves 0-2 (192 threads): stage E as bf16 (800 float4 gathers)
        for (int i = t; i < L_ * 16; i += 192) {
            const int l = i >> 4, qd = i & 15;
            const float4 r = ((const float4*)(item_emb_table + (size_t)idx_sh[l] * D_))[qd];
            ushort4v o = { f2bf(r.x), f2bf(r.y), f2bf(r.z), f2bf(r.w) };
            *(ushort4v*)&eb_sh[l * RS + qd * 4] = o;
        }
    }
    __syncthreads();   // eb / gb ready

    // ---- MFMA gate matmul + fused finalize. Wave w -> P rows [16w,16w+16).
    {
        const int m = lane & 15, q = lane >> 4;
        const int arow = 16 * wave + m;
        const short8 a0 = *(const short8*)&eb_sh[arow * RS + q * 8];       // k 0..31
        const short8 a1 = *(const short8*)&eb_sh[arow * RS + 32 + q * 8];  // k 32..63
#pragma unroll
        for (int n = 0; n < 4; ++n) {
            const int col = 16 * n + m;
            const short8 b0 = *(const short8*)&wbT[col * 64 + q * 8];      // global, L1-hot
            const short8 b1 = *(const short8*)&wbT[col * 64 + 32 + q * 8];
            float4v acc = {0.f, 0.f, 0.f, 0.f};
            acc = __builtin_amdgcn_mfma_f32_16x16x32_bf16(a0, b0, acc, 0, 0, 0);
            acc = __builtin_amdgcn_mfma_f32_16x16x32_bf16(a1, b1, acc, 0, 0, 0);
            const float gbc = gb_sh[col];
#pragma unroll
            for (int r = 0; r < 4; ++r) {
                const int l = 16 * wave + q * 4 + r;   // C/D: row=q*4+r, col=16n+m
                if (l < L_) {
                    const float e = bf2f(eb_sh[l * RS + col]);
                    part_sh[l * SP + col] = e * sigmoidf_(acc[r] + gbc);
                }
            }
        }
    }
    __syncthreads();   // gi ready

    // ---- Phase B partials (waves 0,1: d-halves) + esum (wave 2)
    if (wave < 2) {
        if (lane < L_) {
            const int d0 = 32 * wave;
            float p0 = 0.f, p1 = 0.f, p2 = 0.f, p3 = 0.f;
#pragma unroll
            for (int j = 0; j < 32; j += 4) {
                const int d = d0 + j;
                p0 = fmaf(part_sh[lane * SP + d + 0], ig_item[d + 0], p0);
                p1 = fmaf(part_sh[lane * SP + d + 1], ig_item[d + 1], p1);
                p2 = fmaf(part_sh[lane * SP + d + 2], ig_item[d + 2], p2);
                p3 = fmaf(part_sh[lane * SP + d + 3], ig_item[d + 3], p3);
                p0 = fmaf(u_sh[d + 0], ig_user[(d + 0) * L_ + lane], p0);
                p1 = fmaf(u_sh[d + 1], ig_user[(d + 1) * L_ + lane], p1);
                p2 = fmaf(u_sh[d + 2], ig_user[(d + 2) * L_ + lane], p2);
                p3 = fmaf(u_sh[d + 3], ig_user[(d + 3) * L_ + lane], p3);
            }
            bp_sh[wave][lane] = (p0 + p1) + (p2 + p3);
        }
    } else if (wave == 2) {            // esum[d] = sum_l e[l][d]
        float e0 = 0.f, e1 = 0.f;
#pragma unroll
        for (int l = 0; l < L_; l += 2) {
            e0 += bf2f(eb_sh[l * RS + lane]);
            e1 += bf2f(eb_sh[(l + 1) * RS + lane]);
        }
        esum_sh[lane] = e0 + e1;
    }
    __syncthreads();   // bp / esum ready

    // ---- Phase C: wave 0: s = sigmoid(bp0+bp1); v = u + union/ssum + esum
    if (wave == 0) {
        if (lane < L_) s_sh[lane] = sigmoidf_(bp_sh[0][lane] + bp_sh[1][lane]);
        // same-wave LDS dependency -> lgkmcnt, no barrier
        float a0 = 0.f, a1 = 0.f, ss = 0.f;
        for (int l = 0; l < L_; l += 2) {
            const float sA = s_sh[l], sB = s_sh[l + 1];
            a0 = fmaf(part_sh[l * SP + lane], sA, a0);
            a1 = fmaf(part_sh[(l + 1) * SP + lane], sB, a1);
            ss += sA + sB;
        }
        v_sh[lane] = u_sh[lane] + (a0 + a1) / ss + esum_sh[lane];
    }
    __syncthreads();   // v_sh ready

    // ---- Phase D: 2 threads per (b,t), half-row dots, combine via shfl
    if (t < 2 * T_) {
        const int tt = t >> 1, half = t & 1;
        const int idx = items_to_predict[b * T_ + tt];
        const float* wrow  = W2 + (size_t)idx * D_ + half * 32;
        const float* vhalf = v_sh + half * 32;
        float r0 = 0.f, r1 = 0.f, r2 = 0.f, r3 = 0.f;
#pragma unroll
        for (int kk = 0; kk < 8; ++kk) {
            const float4 w4 = ((const float4*)wrow)[kk];
            const float4 v4 = ((const float4*)vhalf)[kk];
            r0 = fmaf(v4.x, w4.x, r0);
            r1 = fmaf(v4.y, w4.y, r1);
            r2 = fmaf(v4.z, w4.z, r2);
            r3 = fmaf(v4.w, w4.w, r3);
        }
        float r = (r0 + r1) + (r2 + r3);
        r += __shfl_xor(r, 1, 64);
        if (half == 0) out[b * T_ + tt] = r + b2[idx];
    }
}

extern "C" void kernel_launch(void* const* d_in, const int* in_sizes, int n_in,
                              void* d_out, int out_size, void* d_ws, size_t ws_size,
                              hipStream_t stream) {
    const int*   item_seq   = (const int*)d_in[0];
    const int*   user_ids   = (const int*)d_in[1];
    const int*   items_pred = (const int*)d_in[2];
    const float* uet        = (const float*)d_in[3];
    const float* iet        = (const float*)d_in[4];
    const float* fgiW       = (const float*)d_in[5];
    const float* fgib       = (const float*)d_in[6];
    const float* fguW       = (const float*)d_in[7];
    const float* fgub       = (const float*)d_in[8];
    const float* igi        = (const float*)d_in[9];
    const float* igu        = (const float*)d_in[10];
    const float* W2         = (const float*)d_in[11];
    const float* b2t        = (const float*)d_in[12];

    unsigned short* wbT = (unsigned short*)d_ws;   // 8 KB bf16 W^T

    hgn_transpose_w<<<16, 256, 0, stream>>>(fgiW, wbT);
    hgn_fused_kernel<<<B_, 256, 0, stream>>>(
        item_seq, user_ids, items_pred, uet, iet,
        wbT, fgib, fguW, fgub, igi, igu, W2, b2t, (float*)d_out);
}